// Round 10
// baseline (1056.117 us; speedup 1.0000x reference)
//
#include <hip/hip_runtime.h>
#include <hip/hip_fp16.h>

#define NATOMS 24
#define HIDD   61
#define NITERS 6
#define CTOT   132        // c-slots: 128 real + 1 bias + 3 zero
#define QC     33         // c-slots per K-quarter

typedef unsigned short u16;
typedef unsigned int   u32;
typedef _Float16 f16x8 __attribute__((ext_vector_type(8)));
typedef float    f32x4 __attribute__((ext_vector_type(4)));

#define GLOAD_LDS16(g, l) __builtin_amdgcn_global_load_lds( \
    (const __attribute__((address_space(1))) void*)(g), \
    (__attribute__((address_space(3))) void*)(l), 16, 0, 0)

__device__ __forceinline__ float sigm(float x){ return 1.f/(1.f + __expf(-x)); }
__device__ __forceinline__ float tanhx(float x){ return 1.f - 2.f/(__expf(2.f*x)+1.f); }
__device__ __forceinline__ u16 f2h(float f){ return __half_as_ushort(__float2half(f)); }
__device__ __forceinline__ float hbits2f(u16 b){
  union { u16 u; __half h; } cv; cv.u = b; return __half2float(cv.h);
}

__device__ __forceinline__ f16x8 vmul8(f16x8 v, _Float16 s){
  f16x8 r;
  #pragma unroll
  for (int i=0;i<8;++i) r[i] = v[i]*s;
  return r;
}

// ---------------------------------------------------------------------------
__global__ void k_init_h(const int* __restrict__ x, const float* __restrict__ embed,
                         const float* __restrict__ ext, float* __restrict__ h, int N){
  int t = blockIdx.x*blockDim.x + threadIdx.x;
  if (t >= N*64) return;
  int n = t >> 6, k = t & 63;
  float v;
  if (k < HIDD) v = fmaxf(embed[x[n]*HIDD + k], 0.f);
  else          v = ext[n*3 + (k - HIDD)];
  h[t] = v;
}

__global__ void k_transpose_w(const float* __restrict__ Wih, const float* __restrict__ Whh,
                              float* __restrict__ WihT, float* __restrict__ WhhT){
  int t = blockIdx.x*blockDim.x + threadIdx.x;
  if (t >= 192*64) return;
  int j = t / 64, k = t % 64;
  WihT[k*192 + j] = Wih[j*64 + k];
  WhhT[k*192 + j] = Whh[j*64 + k];
}

// ---------------------------------------------------------------------------
// B_glob: fp16 frag-layout of We2R (+bias row c=128, zeros c=129..131),
// 8KB per c-slot: frag fi = c*8 + kh*4 + ct.
// Per frag (1 KB): lane l elem j -> We2R[c][(kh*32+(l>>4)*8+j)*64 + ct*16+(l&15)]
__global__ void k_prep_B(const float* __restrict__ We2, const float* __restrict__ be2,
                         u16* __restrict__ Bg){
  int tid = blockIdx.x*blockDim.x + threadIdx.x;
  if (tid >= CTOT*8*64) return;
  int l  = tid & 63;
  int fi = tid >> 6;            // 0..1055
  int ct = fi & 3;
  int kh = (fi >> 2) & 1;
  int c  = fi >> 3;
  int n  = ct*16 + (l & 15);
  int hb = kh*32 + (l >> 4)*8;
  u16 ov[8];
  #pragma unroll
  for (int j=0;j<8;++j){
    int hh = hb + j;
    float v = 0.f;
    if (c < 128)       v = We2[(size_t)c*4096 + hh*64 + n];
    else if (c == 128) v = be2[hh*64 + n];
    ov[j] = f2h(v);
  }
  uint4 o;
  o.x = (u32)ov[0] | ((u32)ov[1]<<16);
  o.y = (u32)ov[2] | ((u32)ov[3]<<16);
  o.z = (u32)ov[4] | ((u32)ov[5]<<16);
  o.w = (u32)ov[6] | ((u32)ov[7]<<16);
  *(uint4*)&Bg[(size_t)fi*512 + l*8] = o;
}

// ---------------------------------------------------------------------------
// A_glob TRANSPOSED: AgT[e][CTOT] fp16. cols 0..127 = relu(ea@We1+be1),
// col 128 = 1.0, cols 129..131 = 0.
__global__ __launch_bounds__(256) void k_edge_mlp(
    const float* __restrict__ ea, const float* __restrict__ We1,
    const float* __restrict__ be1, u16* __restrict__ AgT, int E, int Epad)
{
  __shared__ float Al[128][66];
  int t = threadIdx.x;
  int e0 = blockIdx.x * 64;
  int el = t & 63, cg = t >> 6;
  int e = e0 + el;
  float4 av = make_float4(0,0,0,0);
  if (e < E) av = *(const float4*)&ea[(size_t)e*4];
  for (int cc = 0; cc < 32; ++cc){
    int c = cg*32 + cc;
    float v = be1[c] + av.x*We1[c] + av.y*We1[128+c] + av.z*We1[256+c] + av.w*We1[384+c];
    Al[c][el] = fmaxf(v, 0.f);
  }
  __syncthreads();
  for (int idx = t; idx < 64*33; idx += 256){
    int el2 = idx / 33, q = idx % 33;
    u16 ov[4];
    #pragma unroll
    for (int i=0;i<4;++i){
      int c = q*4 + i;
      float v;
      if (c < 128)       v = Al[c][el2];
      else if (c == 128) v = 1.f;
      else               v = 0.f;
      ov[i] = f2h(v);
    }
    ushort4 o; o.x=ov[0]; o.y=ov[1]; o.z=ov[2]; o.w=ov[3];
    *(ushort4*)&AgT[(size_t)(e0+el2)*CTOT + q*4] = o;
  }
}

// ---------------------------------------------------------------------------
// Fused msg + segment_sum via MFMA, v9: 512 thr = 8 waves = eg(2) x Kq(4).
// Wave (eg,q): 64 edges, 33 c-slots of K. Each quarter double-buffers its own
// 8 KB chunk (staged by both egs of the quarter); one barrier per c-slot.
// Epilogue: 2-round LDS tree-reduce across quarters; q0 does the atomics.
__global__ __launch_bounds__(512,4) void k_msg_mfma(
    const int* __restrict__ ei, const float* __restrict__ h,
    const u16* __restrict__ AgT, const u16* __restrict__ Bg,
    float* __restrict__ agg, int E, int Epad)
{
  __shared__ __align__(16) u16 Blds[4][2][4096];  // [quarter][buf][8KB]
  int t = threadIdx.x;
  int lane = t & 63;
  int w = t >> 6;            // 0..7
  int q  = w & 3;            // K quarter
  int eg = w >> 2;           // edge half
  int e0 = blockIdx.x * 128;

  // v-frags: lane holds v[e][hb..hb+8), e = eg*64 + rt*16 + (lane&15),
  // hb = kh*32 + (lane>>4)*8.  (all quarters load the same vf for their eg)
  f16x8 vf[4][2];
  #pragma unroll
  for (int rt=0; rt<4; ++rt){
    int e = e0 + eg*64 + rt*16 + (lane&15);
    int src = (e < E) ? ei[e] : 0;
    const float* hp = &h[(size_t)src*64 + (lane>>4)*8];
    #pragma unroll
    for (int kh=0; kh<2; ++kh){
      float4 a = *(const float4*)&hp[kh*32];
      float4 b = *(const float4*)&hp[kh*32+4];
      f16x8 v;
      v[0]=(_Float16)a.x; v[1]=(_Float16)a.y; v[2]=(_Float16)a.z; v[3]=(_Float16)a.w;
      v[4]=(_Float16)b.x; v[5]=(_Float16)b.y; v[6]=(_Float16)b.z; v[7]=(_Float16)b.w;
      vf[rt][kh] = v;
    }
  }

  f32x4 acc[4][4];
  #pragma unroll
  for (int i=0;i<4;++i)
    #pragma unroll
    for (int j=0;j<4;++j)
      acc[i][j] = (f32x4){0.f,0.f,0.f,0.f};

  // A pointers, offset to this quarter's first c-slot
  const u16* Ae[4];
  #pragma unroll
  for (int rt=0; rt<4; ++rt)
    Ae[rt] = AgT + (size_t)(e0 + eg*64 + rt*16 + (lane&15))*CTOT + q*QC;

  _Float16 arP[4], arN[4];
  #pragma unroll
  for (int rt=0;rt<4;++rt) arP[rt] = *(const _Float16*)&Ae[rt][0];

  // prologue: stage c-slot q*33 -> buf 0 (8 KB: 4 rounds x 128 thr x 16 B)
  {
    const char* g = (const char*)(Bg + (size_t)(q*QC)*4096);
    #pragma unroll
    for (int r=0;r<4;++r)
      GLOAD_LDS16(g + r*2048 + (eg*64+lane)*16,
                  (char*)&Blds[q][0][0] + r*2048 + eg*1024 + lane*16);
  }
  __syncthreads();

  int cur = 0;
  for (int ci = 0; ci < QC; ++ci){
    if (ci + 1 < QC){
      const char* g = (const char*)(Bg + (size_t)(q*QC + ci + 1)*4096);
      #pragma unroll
      for (int r=0;r<4;++r)
        GLOAD_LDS16(g + r*2048 + (eg*64+lane)*16,
                    (char*)&Blds[q][cur^1][0] + r*2048 + eg*1024 + lane*16);
      #pragma unroll
      for (int rt=0;rt<4;++rt) arN[rt] = *(const _Float16*)&Ae[rt][ci+1];
    }
    const u16* Bb = &Blds[q][cur][0];
    #pragma unroll
    for (int kh=0; kh<2; ++kh){
      f16x8 g[4];
      #pragma unroll
      for (int rt=0;rt<4;++rt) g[rt] = vmul8(vf[rt][kh], arP[rt]);
      #pragma unroll
      for (int ct=0; ct<4; ++ct){
        f16x8 bf = *(const f16x8*)&Bb[(kh*4+ct)*512 + lane*8];
        #pragma unroll
        for (int rt=0;rt<4;++rt)
          acc[rt][ct] = __builtin_amdgcn_mfma_f32_16x16x32_f16(g[rt], bf, acc[rt][ct], 0,0,0);
      }
    }
    __syncthreads();
    #pragma unroll
    for (int rt=0;rt<4;++rt) arP[rt] = arN[rt];
    cur ^= 1;
  }

  // ---- cross-quarter tree reduce via LDS (B buffers dead; 4 x 16 KB regions)
  // region layout: base r*4096 floats; element (rt,ct,lane) at
  // (rt*4+ct)*256 + lane*4 (f32x4) — stride-1 b128, conflict-free.
  float* accl = (float*)&Blds[0][0][0];
  if (q >= 2){
    int r2 = eg*2 + (q-2);
    #pragma unroll
    for (int rt=0; rt<4; ++rt)
      #pragma unroll
      for (int ct=0; ct<4; ++ct)
        *(f32x4*)&accl[(size_t)r2*4096 + (rt*4+ct)*256 + lane*4] = acc[rt][ct];
  }
  __syncthreads();
  if (q < 2){
    int r2 = eg*2 + q;       // q0 absorbs q2's dump, q1 absorbs q3's
    #pragma unroll
    for (int rt=0; rt<4; ++rt)
      #pragma unroll
      for (int ct=0; ct<4; ++ct)
        acc[rt][ct] += *(const f32x4*)&accl[(size_t)r2*4096 + (rt*4+ct)*256 + lane*4];
  }
  __syncthreads();
  if (q == 1){
    #pragma unroll
    for (int rt=0; rt<4; ++rt)
      #pragma unroll
      for (int ct=0; ct<4; ++ct)
        *(f32x4*)&accl[(size_t)eg*4096 + (rt*4+ct)*256 + lane*4] = acc[rt][ct];
  }
  __syncthreads();
  if (q == 0){
    #pragma unroll
    for (int rt=0; rt<4; ++rt)
      #pragma unroll
      for (int ct=0; ct<4; ++ct)
        acc[rt][ct] += *(const f32x4*)&accl[(size_t)eg*4096 + (rt*4+ct)*256 + lane*4];
    // epilogue: one atomic per edge-k element. D layout: col=lane&15,
    // row=(lane>>4)*4+reg.
    #pragma unroll
    for (int rt=0; rt<4; ++rt){
      #pragma unroll
      for (int r=0; r<4; ++r){
        int el = eg*64 + rt*16 + (lane>>4)*4 + r;
        int e  = e0 + el;
        int dv = (e < E) ? ei[E + e] : -1;
        if (dv >= 0){
          #pragma unroll
          for (int ct=0; ct<4; ++ct)
            unsafeAtomicAdd(&agg[(size_t)dv*64 + ct*16 + (lane&15)], acc[rt][ct][r]);
        }
      }
    }
  }
}

// ---------------------------------------------------------------------------
// combine: m = relu(agg + h@root + conv_b); GRU -> hnext; zeroes agg.
__global__ __launch_bounds__(256) void k_combine(
    const float* __restrict__ hcur, float* __restrict__ agg,
    const float* __restrict__ root, const float* __restrict__ convb,
    const float* __restrict__ WihT, const float* __restrict__ WhhT,
    const float* __restrict__ bih, const float* __restrict__ bhh,
    float* __restrict__ hnext, int N)
{
  __shared__ float hsT[64][76];
  __shared__ float msT[64][76];
  __shared__ float ws[64][68];
  int t = threadIdx.x;
  int n0 = blockIdx.x * 64;

  for (int idx = t; idx < 4096; idx += 256){
    int ni = idx >> 6, k = idx & 63;
    int n = n0 + ni;
    hsT[k][ni] = (n < N) ? hcur[(size_t)n*64 + k] : 0.f;
  }
  for (int idx = t; idx < 4096; idx += 256)
    ws[idx >> 6][idx & 63] = root[idx];
  __syncthreads();

  int tq = t >> 4, tr = t & 15;
  int ni0 = tq*4, j0 = tr*4;

  {
    float acc[4][4];
    #pragma unroll
    for (int i=0;i<4;++i)
      #pragma unroll
      for (int j=0;j<4;++j) acc[i][j] = 0.f;
    for (int k = 0; k < 64; ++k){
      float4 a  = *(const float4*)&hsT[k][ni0];
      float4 wv = *(const float4*)&ws[k][j0];
      float av[4]={a.x,a.y,a.z,a.w}, bv[4]={wv.x,wv.y,wv.z,wv.w};
      #pragma unroll
      for (int i=0;i<4;++i)
        #pragma unroll
        for (int j=0;j<4;++j) acc[i][j] += av[i]*bv[j];
    }
    #pragma unroll
    for (int i=0;i<4;++i){
      int n = n0 + ni0 + i;
      float agv[4] = {0.f,0.f,0.f,0.f};
      if (n < N){
        float4 ag = *(const float4*)&agg[(size_t)n*64 + j0];
        agv[0]=ag.x; agv[1]=ag.y; agv[2]=ag.z; agv[3]=ag.w;
        *(float4*)&agg[(size_t)n*64 + j0] = make_float4(0.f,0.f,0.f,0.f);
      }
      #pragma unroll
      for (int j=0;j<4;++j)
        acc[i][j] = fmaxf(acc[i][j] + agv[j] + convb[j0+j], 0.f);
    }
    #pragma unroll
    for (int j=0;j<4;++j){
      float4 mv; mv.x=acc[0][j]; mv.y=acc[1][j]; mv.z=acc[2][j]; mv.w=acc[3][j];
      *(float4*)&msT[j0+j][ni0] = mv;
    }
  }

  float g[6][4][4];
  #pragma unroll
  for (int ct = 0; ct < 6; ++ct){
    __syncthreads();
    const float* WT = (ct < 3) ? WihT : WhhT;
    const float* bs = (ct < 3) ? bih  : bhh;
    int joff = (ct % 3) * 64;
    for (int idx = t; idx < 4096; idx += 256){
      int k = idx >> 6, j = idx & 63;
      ws[k][j] = WT[k*192 + joff + j];
    }
    __syncthreads();
    float acc[4][4];
    #pragma unroll
    for (int i=0;i<4;++i)
      #pragma unroll
      for (int j=0;j<4;++j) acc[i][j] = bs[joff + j0 + j];
    for (int k = 0; k < 64; ++k){
      float4 a  = (ct < 3) ? *(const float4*)&msT[k][ni0]
                           : *(const float4*)&hsT[k][ni0];
      float4 wv = *(const float4*)&ws[k][j0];
      float av[4]={a.x,a.y,a.z,a.w}, bv[4]={wv.x,wv.y,wv.z,wv.w};
      #pragma unroll
      for (int i=0;i<4;++i)
        #pragma unroll
        for (int j=0;j<4;++j) acc[i][j] += av[i]*bv[j];
    }
    #pragma unroll
    for (int i=0;i<4;++i)
      #pragma unroll
      for (int j=0;j<4;++j) g[ct][i][j] = acc[i][j];
  }

  #pragma unroll
  for (int i=0;i<4;++i){
    int n = n0 + ni0 + i;
    if (n < N){
      float hv[4];
      #pragma unroll
      for (int j=0;j<4;++j){
        float rr = sigm(g[0][i][j] + g[3][i][j]);
        float zz = sigm(g[1][i][j] + g[4][i][j]);
        float hold = hsT[j0+j][ni0+i];
        float nn = tanhx(g[2][i][j] + rr*g[5][i][j]);
        hv[j] = (1.f - zz)*nn + zz*hold;
      }
      float4 o; o.x=hv[0]; o.y=hv[1]; o.z=hv[2]; o.w=hv[3];
      *(float4*)&hnext[(size_t)n*64 + j0] = o;
    }
  }
}

// ---------------------------------------------------------------------------
// final (GEMM-tiled, 64 nodes/block): out-MLP -> norm -> fg_out; then
// classifier (91->256 relu ->18) with LDS-staged weight tiles.
__global__ __launch_bounds__(256,2) void k_final(
    const float* __restrict__ h, const int* __restrict__ x, const float* __restrict__ ext,
    const float* __restrict__ Wo1, const float* __restrict__ bo1,
    const float* __restrict__ Wo2, const float* __restrict__ bo2,
    const float* __restrict__ Wc1, const float* __restrict__ bc1,
    const float* __restrict__ Wc2, const float* __restrict__ bc2,
    float* __restrict__ fg_out, float* __restrict__ pred_out, int N)
{
  __shared__ float fg0[64][68];    // h^T -> out2^T -> fg rows 0..63
  __shared__ float aT [64][68];    // o1^T -> t1^T (per jb)
  __shared__ float fgX[27][68];    // fg rows 64..90
  __shared__ float wst[91][68];    // Wo1 / Wo2 / Wc1 tiles
  __shared__ __half wc2s[256][20]; // Wc2 (cols padded to 20)

  int t = threadIdx.x;
  int n0 = blockIdx.x*64;
  int tq = t >> 4, tr = t & 15;
  int ni0 = tq*4, j0 = tr*4;

  // P0: load h^T, Wo1, Wc2
  for (int idx=t; idx<4096; idx+=256){
    int ni = idx >> 6, k = idx & 63;
    int n = n0 + ni;
    fg0[k][ni] = (n < N) ? h[(size_t)n*64 + k] : 0.f;
  }
  for (int idx=t; idx<4096; idx+=256)
    wst[idx >> 6][idx & 63] = Wo1[idx];
  for (int idx=t; idx<256*20; idx+=256){
    int jj = idx / 20, c = idx % 20;
    wc2s[jj][c] = __float2half(c < 18 ? Wc2[jj*18 + c] : 0.f);
  }
  __syncthreads();

  // P1: o1 = relu(h@Wo1 + bo1) -> aT (transposed)
  {
    float acc[4][4];
    #pragma unroll
    for (int i=0;i<4;++i)
      #pragma unroll
      for (int j=0;j<4;++j) acc[i][j]=0.f;
    for (int k=0;k<64;++k){
      float4 a = *(const float4*)&fg0[k][ni0];
      float4 w = *(const float4*)&wst[k][j0];
      float av[4]={a.x,a.y,a.z,a.w}, wv[4]={w.x,w.y,w.z,w.w};
      #pragma unroll
      for (int i=0;i<4;++i)
        #pragma unroll
        for (int j=0;j<4;++j) acc[i][j] += av[i]*wv[j];
    }
    float b[4]={bo1[j0],bo1[j0+1],bo1[j0+2],bo1[j0+3]};
    #pragma unroll
    for (int i=0;i<4;++i)
      #pragma unroll
      for (int j=0;j<4;++j) aT[j0+j][ni0+i] = fmaxf(acc[i][j]+b[j], 0.f);
  }
  __syncthreads();
  for (int idx=t; idx<4096; idx+=256)
    wst[idx >> 6][idx & 63] = Wo2[idx];
  __syncthreads();

  // P2: out2 = o1@Wo2 + bo2 -> fg0 (h dead)
  {
    float acc[4][4];
    #pragma unroll
    for (int i=0;i<4;++i)
      #pragma unroll
      for (int j=0;j<4;++j) acc[i][j]=0.f;
    for (int k=0;k<64;++k){
      float4 a = *(const float4*)&aT[k][ni0];
      float4 w = *(const float4*)&wst[k][j0];
      float av[4]={a.x,a.y,a.z,a.w}, wv[4]={w.x,w.y,w.z,w.w};
      #pragma unroll
      for (int i=0;i<4;++i)
        #pragma unroll
        for (int j=0;j<4;++j) acc[i][j] += av[i]*wv[j];
    }
    float b[4]={bo2[j0],bo2[j0+1],bo2[j0+2],bo2[j0+3]};
    #pragma unroll
    for (int i=0;i<4;++i)
      #pragma unroll
      for (int j=0;j<4;++j) fg0[j0+j][ni0+i] = acc[i][j]+b[j];
  }
  __syncthreads();

  // P2.5: per-node norm (thread t<64 -> node t); build fgX rows
  if (t < 64){
    int ni = t, n = n0 + ni;
    if (n < N){
      int idxn = x[n];
      float e0=ext[n*3], e1=ext[n*3+1], e2=ext[n*3+2];
      float ss = 1.f + e0*e0 + e1*e1 + e2*e2;   // onehot contributes exactly 1
      for (int j=0;j<64;++j){ float v=fg0[j][ni]; ss += v*v; }
      float rn = 1.f / fmaxf(sqrtf(ss), 1e-12f);
      for (int j=0;j<64;++j) fg0[j][ni] *= rn;
      #pragma unroll
      for (int c=0;c<24;++c) fgX[c][ni] = (c==idxn) ? rn : 0.f;
      fgX[24][ni]=e0*rn; fgX[25][ni]=e1*rn; fgX[26][ni]=e2*rn;
    } else {
      for (int j=0;j<64;++j) fg0[j][ni] = 0.f;
      #pragma unroll
      for (int c=0;c<27;++c) fgX[c][ni] = 0.f;
    }
  }
  __syncthreads();

  // P3: write fg_out
  for (int idx=t; idx<64*91; idx+=256){
    int ni = idx / 91, c = idx % 91;
    int n = n0 + ni;
    if (n < N)
      fg_out[(size_t)n*91 + c] = (c < 64) ? fg0[c][ni] : fgX[c-64][ni];
  }

  // P5: classifier, 4 j-tiles of 64
  float acc2[4][4];
  #pragma unroll
  for (int i=0;i<4;++i)
    #pragma unroll
    for (int cc=0;cc<4;++cc) acc2[i][cc]=0.f;

  for (int jb=0; jb<4; ++jb){
    __syncthreads();
    for (int idx=t; idx<91*64; idx+=256){
      int r = idx >> 6, j = idx & 63;
      wst[r][j] = Wc1[r*256 + jb*64 + j];
    }
    __syncthreads();
    float acc[4][4];
    {
      float b[4]={bc1[jb*64+j0],bc1[jb*64+j0+1],bc1[jb*64+j0+2],bc1[jb*64+j0+3]};
      #pragma unroll
      for (int i=0;i<4;++i)
        #pragma unroll
        for (int j=0;j<4;++j) acc[i][j]=b[j];
    }
    for (int k=0;k<91;++k){
      const float* arow = (k < 64) ? &fg0[k][ni0] : &fgX[k-64][ni0];
      float4 a = *(const float4*)arow;
      float4 w = *(const float4*)&wst[k][j0];
      float av[4]={a.x,a.y,a.z,a.w}, wv[4]={w.x,w.y,w.z,w.w};
      #pragma unroll
      for (int i=0;i<4;++i)
        #pragma unroll
        for (int j=0;j<4;++j) acc[i][j] += av[i]*wv[j];
    }
    #pragma unroll
    for (int i=0;i<4;++i)
      #pragma unroll
      for (int j=0;j<4;++j) aT[j0+j][ni0+i] = fmaxf(acc[i][j], 0.f);
    __syncthreads();
    if (tr < 5){
      for (int j=0;j<64;++j){
        float4 tv = *(const float4*)&aT[j][ni0];
        float tvv[4]={tv.x,tv.y,tv.z,tv.w};
        int jj = jb*64 + j;
        ushort4 uw = *(const ushort4*)&wc2s[jj][tr*4];
        float w0=hbits2f(uw.x), w1=hbits2f(uw.y), w2=hbits2f(uw.z), w3=hbits2f(uw.w);
        float wv[4]={w0,w1,w2,w3};
        #pragma unroll
        for (int i=0;i<4;++i)
          #pragma unroll
          for (int cc=0;cc<4;++cc) acc2[i][cc] += tvv[i]*wv[cc];
      }
    }
  }

  // P6: write pred
  if (tr < 5){
    #pragma unroll
    for (int i=0;i<4;++i){
      int n = n0 + ni0 + i;
      if (n < N){
        #pragma unroll
        for (int cc=0;cc<4;++cc){
          int c = tr*4 + cc;
          if (c < 18) pred_out[(size_t)n*18 + c] = acc2[i][cc] + bc2[c];
        }
      }
    }
  }
}

// ---------------------------------------------------------------------------
extern "C" void kernel_launch(void* const* d_in, const int* in_sizes, int n_in,
                              void* d_out, int out_size, void* d_ws, size_t ws_size,
                              hipStream_t stream)
{
  const int*   x    = (const int*)d_in[0];
  const int*   ei   = (const int*)d_in[1];
  const float* ea   = (const float*)d_in[2];
  const float* ext  = (const float*)d_in[3];
  const float* embed= (const float*)d_in[4];
  const float* We1  = (const float*)d_in[5];
  const float* be1  = (const float*)d_in[6];
  const float* We2  = (const float*)d_in[7];
  const float* be2  = (const float*)d_in[8];
  const float* root = (const float*)d_in[9];
  const float* convb= (const float*)d_in[10];
  const float* Wih  = (const float*)d_in[11];
  const float* Whh  = (const float*)d_in[12];
  const float* bih  = (const float*)d_in[13];
  const float* bhh  = (const float*)d_in[14];
  const float* Wo1  = (const float*)d_in[15];
  const float* bo1  = (const float*)d_in[16];
  const float* Wo2  = (const float*)d_in[17];
  const float* bo2  = (const float*)d_in[18];
  const float* Wc1  = (const float*)d_in[19];
  const float* bc1  = (const float*)d_in[20];
  const float* Wc2  = (const float*)d_in[21];
  const float* bc2  = (const float*)d_in[22];
  int N = in_sizes[0];
  int E = in_sizes[1] / 2;
  float* out = (float*)d_out;
  float* fg_out = out;
  float* pred_out = out + (size_t)N*91;

  int nblk256 = (E + 255) / 256;
  int Epad = nblk256 * 256;
  int nblk128 = (E + 127) / 128;

  char* w = (char*)d_ws;
  size_t remain = ws_size;
  auto alloc = [&](size_t bytes)->char*{
    size_t rb = (bytes + 255) & ~(size_t)255;
    if (rb > remain) return (char*)0;
    char* p = w; w += rb; remain -= rb; return p;
  };
  float* h_a  = (float*)alloc((size_t)N*64*4);
  float* h_b  = (float*)alloc((size_t)N*64*4);
  float* agg  = (float*)alloc((size_t)N*64*4);
  float* WihT = (float*)alloc(64*192*4);
  float* WhhT = (float*)alloc(64*192*4);
  u16*   AgT  = (u16*)alloc((size_t)Epad*CTOT*2);
  u16*   Bg   = (u16*)alloc((size_t)CTOT*8192);
  if (!h_a || !h_b || !agg || !WihT || !WhhT || !AgT || !Bg) return;

  k_init_h<<<dim3((N*64 + 255)/256), dim3(256), 0, stream>>>(x, embed, ext, h_a, N);
  k_transpose_w<<<dim3(48), dim3(256), 0, stream>>>(Wih, Whh, WihT, WhhT);
  k_prep_B<<<dim3((CTOT*8*64 + 255)/256), dim3(256), 0, stream>>>(We2, be2, Bg);
  k_edge_mlp<<<dim3(Epad/64), dim3(256), 0, stream>>>(ea, We1, be1, AgT, E, Epad);
  hipMemsetAsync(agg, 0, (size_t)N*64*4, stream);

  float* hc = h_a; float* hn = h_b;
  for (int it = 0; it < NITERS; ++it){
    k_msg_mfma<<<dim3(nblk128), dim3(512), 0, stream>>>(ei, hc, AgT, Bg, agg, E, Epad);
    k_combine<<<dim3((N + 63)/64), dim3(256), 0, stream>>>(
        hc, agg, root, convb, WihT, WhhT, bih, bhh, hn, N);
    float* tmp = hc; hc = hn; hn = tmp;
  }

  k_final<<<dim3((N + 63)/64), dim3(256), 0, stream>>>(
      hc, x, ext, Wo1, bo1, Wo2, bo2, Wc1, bc1, Wc2, bc2, fg_out, pred_out, N);
}

// Round 11
// 721.108 us; speedup vs baseline: 1.4646x; 1.4646x over previous
//
#include <hip/hip_runtime.h>
#include <hip/hip_fp16.h>

#define NATOMS 24
#define HIDD   61
#define NITERS 6
#define CTOT   132        // c-slots: 128 real + 1 bias + 3 zero
#define HC     66         // c-slots per K-half

typedef unsigned short u16;
typedef unsigned int   u32;
typedef _Float16 f16x8 __attribute__((ext_vector_type(8)));
typedef _Float16 f16x2 __attribute__((ext_vector_type(2)));
typedef float    f32x4 __attribute__((ext_vector_type(4)));

#define GLOAD_LDS16(g, l) __builtin_amdgcn_global_load_lds( \
    (const __attribute__((address_space(1))) void*)(g), \
    (__attribute__((address_space(3))) void*)(l), 16, 0, 0)

__device__ __forceinline__ float sigm(float x){ return 1.f/(1.f + __expf(-x)); }
__device__ __forceinline__ float tanhx(float x){ return 1.f - 2.f/(__expf(2.f*x)+1.f); }
__device__ __forceinline__ u16 f2h(float f){ return __half_as_ushort(__float2half(f)); }
__device__ __forceinline__ float hbits2f(u16 b){
  union { u16 u; __half h; } cv; cv.u = b; return __half2float(cv.h);
}

__device__ __forceinline__ f16x8 vmul8(f16x8 v, _Float16 s){
  f16x8 r;
  #pragma unroll
  for (int i=0;i<8;++i) r[i] = v[i]*s;
  return r;
}

// ---------------------------------------------------------------------------
__global__ void k_init_h(const int* __restrict__ x, const float* __restrict__ embed,
                         const float* __restrict__ ext, float* __restrict__ h, int N){
  int t = blockIdx.x*blockDim.x + threadIdx.x;
  if (t >= N*64) return;
  int n = t >> 6, k = t & 63;
  float v;
  if (k < HIDD) v = fmaxf(embed[x[n]*HIDD + k], 0.f);
  else          v = ext[n*3 + (k - HIDD)];
  h[t] = v;
}

__global__ void k_transpose_w(const float* __restrict__ Wih, const float* __restrict__ Whh,
                              float* __restrict__ WihT, float* __restrict__ WhhT){
  int t = blockIdx.x*blockDim.x + threadIdx.x;
  if (t >= 192*64) return;
  int j = t / 64, k = t % 64;
  WihT[k*192 + j] = Wih[j*64 + k];
  WhhT[k*192 + j] = Whh[j*64 + k];
}

// ---------------------------------------------------------------------------
// B_glob: fp16 frag-layout of We2R (+bias row c=128, zeros c=129..131),
// 8KB per c-slot: frag fi = c*8 + kh*4 + ct.
// Per frag (1 KB): lane l elem j -> We2R[c][(kh*32+(l>>4)*8+j)*64 + ct*16+(l&15)]
__global__ void k_prep_B(const float* __restrict__ We2, const float* __restrict__ be2,
                         u16* __restrict__ Bg){
  int tid = blockIdx.x*blockDim.x + threadIdx.x;
  if (tid >= CTOT*8*64) return;
  int l  = tid & 63;
  int fi = tid >> 6;            // 0..1055
  int ct = fi & 3;
  int kh = (fi >> 2) & 1;
  int c  = fi >> 3;
  int n  = ct*16 + (l & 15);
  int hb = kh*32 + (l >> 4)*8;
  u16 ov[8];
  #pragma unroll
  for (int j=0;j<8;++j){
    int hh = hb + j;
    float v = 0.f;
    if (c < 128)       v = We2[(size_t)c*4096 + hh*64 + n];
    else if (c == 128) v = be2[hh*64 + n];
    ov[j] = f2h(v);
  }
  uint4 o;
  o.x = (u32)ov[0] | ((u32)ov[1]<<16);
  o.y = (u32)ov[2] | ((u32)ov[3]<<16);
  o.z = (u32)ov[4] | ((u32)ov[5]<<16);
  o.w = (u32)ov[6] | ((u32)ov[7]<<16);
  *(uint4*)&Bg[(size_t)fi*512 + l*8] = o;
}

// ---------------------------------------------------------------------------
// A_glob TRANSPOSED: AgT[e][CTOT] fp16. cols 0..127 = relu(ea@We1+be1),
// col 128 = 1.0, cols 129..131 = 0.
__global__ __launch_bounds__(256) void k_edge_mlp(
    const float* __restrict__ ea, const float* __restrict__ We1,
    const float* __restrict__ be1, u16* __restrict__ AgT, int E, int Epad)
{
  __shared__ float Al[128][66];
  int t = threadIdx.x;
  int e0 = blockIdx.x * 64;
  int el = t & 63, cg = t >> 6;
  int e = e0 + el;
  float4 av = make_float4(0,0,0,0);
  if (e < E) av = *(const float4*)&ea[(size_t)e*4];
  for (int cc = 0; cc < 32; ++cc){
    int c = cg*32 + cc;
    float v = be1[c] + av.x*We1[c] + av.y*We1[128+c] + av.z*We1[256+c] + av.w*We1[384+c];
    Al[c][el] = fmaxf(v, 0.f);
  }
  __syncthreads();
  for (int idx = t; idx < 64*33; idx += 256){
    int el2 = idx / 33, q = idx % 33;
    u16 ov[4];
    #pragma unroll
    for (int i=0;i<4;++i){
      int c = q*4 + i;
      float v;
      if (c < 128)       v = Al[c][el2];
      else if (c == 128) v = 1.f;
      else               v = 0.f;
      ov[i] = f2h(v);
    }
    ushort4 o; o.x=ov[0]; o.y=ov[1]; o.z=ov[2]; o.w=ov[3];
    *(ushort4*)&AgT[(size_t)(e0+el2)*CTOT + q*4] = o;
  }
}

// ---------------------------------------------------------------------------
// Fused msg + segment_sum via MFMA, v10: 512 thr = 8 waves = eg(4) x half(2).
// Wave (eg,half): 32 edges (rt=2), one K-half of 66 c-slots (33 chunks of
// 16 KB). Per-wave regs ~80 (acc[2][4]=32, vf[2][2]=16) -> no spill at the
// 128-reg cap from __launch_bounds__(512,4). Each half double-buffers its
// chunk (staged by its 4 waves); one barrier per chunk. Epilogue: half-1
// dumps acc to LDS (dead B-bufs), half-0 reduces + one atomic per element.
__global__ __launch_bounds__(512,4) void k_msg_mfma(
    const int* __restrict__ ei, const float* __restrict__ h,
    const u16* __restrict__ AgT, const u16* __restrict__ Bg,
    float* __restrict__ agg, int E, int Epad)
{
  __shared__ __align__(16) u16 Blds[2][2][8192];  // [half][buf][16KB]
  __shared__ int dstl[128];
  int t = threadIdx.x;
  int lane = t & 63;
  int w = t >> 6;            // 0..7
  int eg = w & 3;            // 32-edge group
  int half = w >> 2;         // K half
  int e0 = blockIdx.x * 128;
  int slot0 = half * HC;     // first c-slot of this half

  if (t < 128) dstl[t] = (e0 + t < E) ? ei[E + e0 + t] : -1;

  // v-frags: lane holds v[e][hb..hb+8), e = eg*32 + rt*16 + (lane&15),
  // hb = kh*32 + (lane>>4)*8.  (both halves load the same vf for their eg)
  f16x8 vf[2][2];
  #pragma unroll
  for (int rt=0; rt<2; ++rt){
    int e = e0 + eg*32 + rt*16 + (lane&15);
    int src = (e < E) ? ei[e] : 0;
    const float* hp = &h[(size_t)src*64 + (lane>>4)*8];
    #pragma unroll
    for (int kh=0; kh<2; ++kh){
      float4 a = *(const float4*)&hp[kh*32];
      float4 b = *(const float4*)&hp[kh*32+4];
      f16x8 v;
      v[0]=(_Float16)a.x; v[1]=(_Float16)a.y; v[2]=(_Float16)a.z; v[3]=(_Float16)a.w;
      v[4]=(_Float16)b.x; v[5]=(_Float16)b.y; v[6]=(_Float16)b.z; v[7]=(_Float16)b.w;
      vf[rt][kh] = v;
    }
  }

  f32x4 acc[2][4];
  #pragma unroll
  for (int i=0;i<2;++i)
    #pragma unroll
    for (int j=0;j<4;++j)
      acc[i][j] = (f32x4){0.f,0.f,0.f,0.f};

  // A pointers, offset to this half's first c-slot
  const u16* Ae[2];
  #pragma unroll
  for (int rt=0; rt<2; ++rt)
    Ae[rt] = AgT + (size_t)(e0 + eg*32 + rt*16 + (lane&15))*CTOT + slot0;

  union UA { ushort2 u; f16x2 h; };
  f16x2 arP[2], arN[2];
  #pragma unroll
  for (int rt=0;rt<2;++rt){
    UA ua; ua.u = *(const ushort2*)&Ae[rt][0];
    arP[rt] = ua.h;
  }

  // prologue: stage chunk 0 -> buf 0 (16 KB: 4 rounds x 4 egs x 64 lanes x 16B)
  {
    const char* g = (const char*)(Bg + (size_t)slot0*4096);
    #pragma unroll
    for (int r=0;r<4;++r)
      GLOAD_LDS16(g + r*4096 + eg*1024 + lane*16,
                  (char*)&Blds[half][0][0] + r*4096 + eg*1024);
  }
  __syncthreads();

  int cur = 0;
  for (int ci = 0; ci < 33; ++ci){
    if (ci + 1 < 33){
      const char* g = (const char*)(Bg + (size_t)(slot0 + (ci+1)*2)*4096);
      #pragma unroll
      for (int r=0;r<4;++r)
        GLOAD_LDS16(g + r*4096 + eg*1024 + lane*16,
                    (char*)&Blds[half][cur^1][0] + r*4096 + eg*1024);
      #pragma unroll
      for (int rt=0;rt<2;++rt){
        UA ua; ua.u = *(const ushort2*)&Ae[rt][(ci+1)*2];
        arN[rt] = ua.h;
      }
    }
    const u16* Bb = &Blds[half][cur][0];
    #pragma unroll
    for (int cl=0; cl<2; ++cl){
      #pragma unroll
      for (int kh=0; kh<2; ++kh){
        f16x8 g0 = vmul8(vf[0][kh], arP[0][cl]);
        f16x8 g1 = vmul8(vf[1][kh], arP[1][cl]);
        #pragma unroll
        for (int ct=0; ct<4; ++ct){
          f16x8 bf = *(const f16x8*)&Bb[(cl*8 + kh*4 + ct)*512 + lane*8];
          acc[0][ct] = __builtin_amdgcn_mfma_f32_16x16x32_f16(g0, bf, acc[0][ct], 0,0,0);
          acc[1][ct] = __builtin_amdgcn_mfma_f32_16x16x32_f16(g1, bf, acc[1][ct], 0,0,0);
        }
      }
    }
    __syncthreads();
    #pragma unroll
    for (int rt=0;rt<2;++rt) arP[rt] = arN[rt];
    cur ^= 1;
  }

  // ---- cross-half reduce via LDS (B buffers dead; need 32 KB).
  // element (eg,rt,ct): f32x4 at (eg*8 + rt*4 + ct)*256 + lane*4 — stride-1
  // b128, conflict-free.
  float* accl = (float*)&Blds[0][0][0];
  if (half == 1){
    #pragma unroll
    for (int rt=0; rt<2; ++rt)
      #pragma unroll
      for (int ct=0; ct<4; ++ct)
        *(f32x4*)&accl[(size_t)(eg*8 + rt*4 + ct)*256 + lane*4] = acc[rt][ct];
  }
  __syncthreads();
  if (half == 0){
    #pragma unroll
    for (int rt=0; rt<2; ++rt)
      #pragma unroll
      for (int ct=0; ct<4; ++ct)
        acc[rt][ct] += *(const f32x4*)&accl[(size_t)(eg*8 + rt*4 + ct)*256 + lane*4];
    // epilogue: one atomic per edge-k element. D layout: col=lane&15,
    // row=(lane>>4)*4+reg.
    #pragma unroll
    for (int rt=0; rt<2; ++rt){
      #pragma unroll
      for (int r=0; r<4; ++r){
        int el = eg*32 + rt*16 + (lane>>4)*4 + r;
        int dv = dstl[el];
        if (dv >= 0){
          #pragma unroll
          for (int ct=0; ct<4; ++ct)
            unsafeAtomicAdd(&agg[(size_t)dv*64 + ct*16 + (lane&15)], acc[rt][ct][r]);
        }
      }
    }
  }
}

// ---------------------------------------------------------------------------
// combine: m = relu(agg + h@root + conv_b); GRU -> hnext; zeroes agg.
__global__ __launch_bounds__(256) void k_combine(
    const float* __restrict__ hcur, float* __restrict__ agg,
    const float* __restrict__ root, const float* __restrict__ convb,
    const float* __restrict__ WihT, const float* __restrict__ WhhT,
    const float* __restrict__ bih, const float* __restrict__ bhh,
    float* __restrict__ hnext, int N)
{
  __shared__ float hsT[64][76];
  __shared__ float msT[64][76];
  __shared__ float ws[64][68];
  int t = threadIdx.x;
  int n0 = blockIdx.x * 64;

  for (int idx = t; idx < 4096; idx += 256){
    int ni = idx >> 6, k = idx & 63;
    int n = n0 + ni;
    hsT[k][ni] = (n < N) ? hcur[(size_t)n*64 + k] : 0.f;
  }
  for (int idx = t; idx < 4096; idx += 256)
    ws[idx >> 6][idx & 63] = root[idx];
  __syncthreads();

  int tq = t >> 4, tr = t & 15;
  int ni0 = tq*4, j0 = tr*4;

  {
    float acc[4][4];
    #pragma unroll
    for (int i=0;i<4;++i)
      #pragma unroll
      for (int j=0;j<4;++j) acc[i][j] = 0.f;
    for (int k = 0; k < 64; ++k){
      float4 a  = *(const float4*)&hsT[k][ni0];
      float4 wv = *(const float4*)&ws[k][j0];
      float av[4]={a.x,a.y,a.z,a.w}, bv[4]={wv.x,wv.y,wv.z,wv.w};
      #pragma unroll
      for (int i=0;i<4;++i)
        #pragma unroll
        for (int j=0;j<4;++j) acc[i][j] += av[i]*bv[j];
    }
    #pragma unroll
    for (int i=0;i<4;++i){
      int n = n0 + ni0 + i;
      float agv[4] = {0.f,0.f,0.f,0.f};
      if (n < N){
        float4 ag = *(const float4*)&agg[(size_t)n*64 + j0];
        agv[0]=ag.x; agv[1]=ag.y; agv[2]=ag.z; agv[3]=ag.w;
        *(float4*)&agg[(size_t)n*64 + j0] = make_float4(0.f,0.f,0.f,0.f);
      }
      #pragma unroll
      for (int j=0;j<4;++j)
        acc[i][j] = fmaxf(acc[i][j] + agv[j] + convb[j0+j], 0.f);
    }
    #pragma unroll
    for (int j=0;j<4;++j){
      float4 mv; mv.x=acc[0][j]; mv.y=acc[1][j]; mv.z=acc[2][j]; mv.w=acc[3][j];
      *(float4*)&msT[j0+j][ni0] = mv;
    }
  }

  float g[6][4][4];
  #pragma unroll
  for (int ct = 0; ct < 6; ++ct){
    __syncthreads();
    const float* WT = (ct < 3) ? WihT : WhhT;
    const float* bs = (ct < 3) ? bih  : bhh;
    int joff = (ct % 3) * 64;
    for (int idx = t; idx < 4096; idx += 256){
      int k = idx >> 6, j = idx & 63;
      ws[k][j] = WT[k*192 + joff + j];
    }
    __syncthreads();
    float acc[4][4];
    #pragma unroll
    for (int i=0;i<4;++i)
      #pragma unroll
      for (int j=0;j<4;++j) acc[i][j] = bs[joff + j0 + j];
    for (int k = 0; k < 64; ++k){
      float4 a  = (ct < 3) ? *(const float4*)&msT[k][ni0]
                           : *(const float4*)&hsT[k][ni0];
      float4 wv = *(const float4*)&ws[k][j0];
      float av[4]={a.x,a.y,a.z,a.w}, bv[4]={wv.x,wv.y,wv.z,wv.w};
      #pragma unroll
      for (int i=0;i<4;++i)
        #pragma unroll
        for (int j=0;j<4;++j) acc[i][j] += av[i]*bv[j];
    }
    #pragma unroll
    for (int i=0;i<4;++i)
      #pragma unroll
      for (int j=0;j<4;++j) g[ct][i][j] = acc[i][j];
  }

  #pragma unroll
  for (int i=0;i<4;++i){
    int n = n0 + ni0 + i;
    if (n < N){
      float hv[4];
      #pragma unroll
      for (int j=0;j<4;++j){
        float rr = sigm(g[0][i][j] + g[3][i][j]);
        float zz = sigm(g[1][i][j] + g[4][i][j]);
        float hold = hsT[j0+j][ni0+i];
        float nn = tanhx(g[2][i][j] + rr*g[5][i][j]);
        hv[j] = (1.f - zz)*nn + zz*hold;
      }
      float4 o; o.x=hv[0]; o.y=hv[1]; o.z=hv[2]; o.w=hv[3];
      *(float4*)&hnext[(size_t)n*64 + j0] = o;
    }
  }
}

// ---------------------------------------------------------------------------
// final (GEMM-tiled, 64 nodes/block): out-MLP -> norm -> fg_out; then
// classifier (91->256 relu ->18) with LDS-staged weight tiles.
__global__ __launch_bounds__(256,2) void k_final(
    const float* __restrict__ h, const int* __restrict__ x, const float* __restrict__ ext,
    const float* __restrict__ Wo1, const float* __restrict__ bo1,
    const float* __restrict__ Wo2, const float* __restrict__ bo2,
    const float* __restrict__ Wc1, const float* __restrict__ bc1,
    const float* __restrict__ Wc2, const float* __restrict__ bc2,
    float* __restrict__ fg_out, float* __restrict__ pred_out, int N)
{
  __shared__ float fg0[64][68];    // h^T -> out2^T -> fg rows 0..63
  __shared__ float aT [64][68];    // o1^T -> t1^T (per jb)
  __shared__ float fgX[27][68];    // fg rows 64..90
  __shared__ float wst[91][68];    // Wo1 / Wo2 / Wc1 tiles
  __shared__ __half wc2s[256][20]; // Wc2 (cols padded to 20)

  int t = threadIdx.x;
  int n0 = blockIdx.x*64;
  int tq = t >> 4, tr = t & 15;
  int ni0 = tq*4, j0 = tr*4;

  // P0: load h^T, Wo1, Wc2
  for (int idx=t; idx<4096; idx+=256){
    int ni = idx >> 6, k = idx & 63;
    int n = n0 + ni;
    fg0[k][ni] = (n < N) ? h[(size_t)n*64 + k] : 0.f;
  }
  for (int idx=t; idx<4096; idx+=256)
    wst[idx >> 6][idx & 63] = Wo1[idx];
  for (int idx=t; idx<256*20; idx+=256){
    int jj = idx / 20, c = idx % 20;
    wc2s[jj][c] = __float2half(c < 18 ? Wc2[jj*18 + c] : 0.f);
  }
  __syncthreads();

  // P1: o1 = relu(h@Wo1 + bo1) -> aT (transposed)
  {
    float acc[4][4];
    #pragma unroll
    for (int i=0;i<4;++i)
      #pragma unroll
      for (int j=0;j<4;++j) acc[i][j]=0.f;
    for (int k=0;k<64;++k){
      float4 a = *(const float4*)&fg0[k][ni0];
      float4 w = *(const float4*)&wst[k][j0];
      float av[4]={a.x,a.y,a.z,a.w}, wv[4]={w.x,w.y,w.z,w.w};
      #pragma unroll
      for (int i=0;i<4;++i)
        #pragma unroll
        for (int j=0;j<4;++j) acc[i][j] += av[i]*wv[j];
    }
    float b[4]={bo1[j0],bo1[j0+1],bo1[j0+2],bo1[j0+3]};
    #pragma unroll
    for (int i=0;i<4;++i)
      #pragma unroll
      for (int j=0;j<4;++j) aT[j0+j][ni0+i] = fmaxf(acc[i][j]+b[j], 0.f);
  }
  __syncthreads();
  for (int idx=t; idx<4096; idx+=256)
    wst[idx >> 6][idx & 63] = Wo2[idx];
  __syncthreads();

  // P2: out2 = o1@Wo2 + bo2 -> fg0 (h dead)
  {
    float acc[4][4];
    #pragma unroll
    for (int i=0;i<4;++i)
      #pragma unroll
      for (int j=0;j<4;++j) acc[i][j]=0.f;
    for (int k=0;k<64;++k){
      float4 a = *(const float4*)&aT[k][ni0];
      float4 w = *(const float4*)&wst[k][j0];
      float av[4]={a.x,a.y,a.z,a.w}, wv[4]={w.x,w.y,w.z,w.w};
      #pragma unroll
      for (int i=0;i<4;++i)
        #pragma unroll
        for (int j=0;j<4;++j) acc[i][j] += av[i]*wv[j];
    }
    float b[4]={bo2[j0],bo2[j0+1],bo2[j0+2],bo2[j0+3]};
    #pragma unroll
    for (int i=0;i<4;++i)
      #pragma unroll
      for (int j=0;j<4;++j) fg0[j0+j][ni0+i] = acc[i][j]+b[j];
  }
  __syncthreads();

  // P2.5: per-node norm (thread t<64 -> node t); build fgX rows
  if (t < 64){
    int ni = t, n = n0 + ni;
    if (n < N){
      int idxn = x[n];
      float e0=ext[n*3], e1=ext[n*3+1], e2=ext[n*3+2];
      float ss = 1.f + e0*e0 + e1*e1 + e2*e2;   // onehot contributes exactly 1
      for (int j=0;j<64;++j){ float v=fg0[j][ni]; ss += v*v; }
      float rn = 1.f / fmaxf(sqrtf(ss), 1e-12f);
      for (int j=0;j<64;++j) fg0[j][ni] *= rn;
      #pragma unroll
      for (int c=0;c<24;++c) fgX[c][ni] = (c==idxn) ? rn : 0.f;
      fgX[24][ni]=e0*rn; fgX[25][ni]=e1*rn; fgX[26][ni]=e2*rn;
    } else {
      for (int j=0;j<64;++j) fg0[j][ni] = 0.f;
      #pragma unroll
      for (int c=0;c<27;++c) fgX[c][ni] = 0.f;
    }
  }
  __syncthreads();

  // P3: write fg_out
  for (int idx=t; idx<64*91; idx+=256){
    int ni = idx / 91, c = idx % 91;
    int n = n0 + ni;
    if (n < N)
      fg_out[(size_t)n*91 + c] = (c < 64) ? fg0[c][ni] : fgX[c-64][ni];
  }

  // P5: classifier, 4 j-tiles of 64
  float acc2[4][4];
  #pragma unroll
  for (int i=0;i<4;++i)
    #pragma unroll
    for (int cc=0;cc<4;++cc) acc2[i][cc]=0.f;

  for (int jb=0; jb<4; ++jb){
    __syncthreads();
    for (int idx=t; idx<91*64; idx+=256){
      int r = idx >> 6, j = idx & 63;
      wst[r][j] = Wc1[r*256 + jb*64 + j];
    }
    __syncthreads();
    float acc[4][4];
    {
      float b[4]={bc1[jb*64+j0],bc1[jb*64+j0+1],bc1[jb*64+j0+2],bc1[jb*64+j0+3]};
      #pragma unroll
      for (int i=0;i<4;++i)
        #pragma unroll
        for (int j=0;j<4;++j) acc[i][j]=b[j];
    }
    for (int k=0;k<91;++k){
      const float* arow = (k < 64) ? &fg0[k][ni0] : &fgX[k-64][ni0];
      float4 a = *(const float4*)arow;
      float4 w = *(const float4*)&wst[k][j0];
      float av[4]={a.x,a.y,a.z,a.w}, wv[4]={w.x,w.y,w.z,w.w};
      #pragma unroll
      for (int i=0;i<4;++i)
        #pragma unroll
        for (int j=0;j<4;++j) acc[i][j] += av[i]*wv[j];
    }
    #pragma unroll
    for (int i=0;i<4;++i)
      #pragma unroll
      for (int j=0;j<4;++j) aT[j0+j][ni0+i] = fmaxf(acc[i][j], 0.f);
    __syncthreads();
    if (tr < 5){
      for (int j=0;j<64;++j){
        float4 tv = *(const float4*)&aT[j][ni0];
        float tvv[4]={tv.x,tv.y,tv.z,tv.w};
        int jj = jb*64 + j;
        ushort4 uw = *(const ushort4*)&wc2s[jj][tr*4];
        float w0=hbits2f(uw.x), w1=hbits2f(uw.y), w2=hbits2f(uw.z), w3=hbits2f(uw.w);
        float wv[4]={w0,w1,w2,w3};
        #pragma unroll
        for (int i=0;i<4;++i)
          #pragma unroll
          for (int cc=0;cc<4;++cc) acc2[i][cc] += tvv[i]*wv[cc];
      }
    }
  }

  // P6: write pred
  if (tr < 5){
    #pragma unroll
    for (int i=0;i<4;++i){
      int n = n0 + ni0 + i;
      if (n < N){
        #pragma unroll
        for (int cc=0;cc<4;++cc){
          int c = tr*4 + cc;
          if (c < 18) pred_out[(size_t)n*18 + c] = acc2[i][cc] + bc2[c];
        }
      }
    }
  }
}

// ---------------------------------------------------------------------------
extern "C" void kernel_launch(void* const* d_in, const int* in_sizes, int n_in,
                              void* d_out, int out_size, void* d_ws, size_t ws_size,
                              hipStream_t stream)
{
  const int*   x    = (const int*)d_in[0];
  const int*   ei   = (const int*)d_in[1];
  const float* ea   = (const float*)d_in[2];
  const float* ext  = (const float*)d_in[3];
  const float* embed= (const float*)d_in[4];
  const float* We1  = (const float*)d_in[5];
  const float* be1  = (const float*)d_in[6];
  const float* We2  = (const float*)d_in[7];
  const float* be2  = (const float*)d_in[8];
  const float* root = (const float*)d_in[9];
  const float* convb= (const float*)d_in[10];
  const float* Wih  = (const float*)d_in[11];
  const float* Whh  = (const float*)d_in[12];
  const float* bih  = (const float*)d_in[13];
  const float* bhh  = (const float*)d_in[14];
  const float* Wo1  = (const float*)d_in[15];
  const float* bo1  = (const float*)d_in[16];
  const float* Wo2  = (const float*)d_in[17];
  const float* bo2  = (const float*)d_in[18];
  const float* Wc1  = (const float*)d_in[19];
  const float* bc1  = (const float*)d_in[20];
  const float* Wc2  = (const float*)d_in[21];
  const float* bc2  = (const float*)d_in[22];
  int N = in_sizes[0];
  int E = in_sizes[1] / 2;
  float* out = (float*)d_out;
  float* fg_out = out;
  float* pred_out = out + (size_t)N*91;

  int nblk256 = (E + 255) / 256;
  int Epad = nblk256 * 256;
  int nblk128 = (E + 127) / 128;

  char* w = (char*)d_ws;
  size_t remain = ws_size;
  auto alloc = [&](size_t bytes)->char*{
    size_t rb = (bytes + 255) & ~(size_t)255;
    if (rb > remain) return (char*)0;
    char* p = w; w += rb; remain -= rb; return p;
  };
  float* h_a  = (float*)alloc((size_t)N*64*4);
  float* h_b  = (float*)alloc((size_t)N*64*4);
  float* agg  = (float*)alloc((size_t)N*64*4);
  float* WihT = (float*)alloc(64*192*4);
  float* WhhT = (float*)alloc(64*192*4);
  u16*   AgT  = (u16*)alloc((size_t)Epad*CTOT*2);
  u16*   Bg   = (u16*)alloc((size_t)CTOT*8192);
  if (!h_a || !h_b || !agg || !WihT || !WhhT || !AgT || !Bg) return;

  k_init_h<<<dim3((N*64 + 255)/256), dim3(256), 0, stream>>>(x, embed, ext, h_a, N);
  k_transpose_w<<<dim3(48), dim3(256), 0, stream>>>(Wih, Whh, WihT, WhhT);
  k_prep_B<<<dim3((CTOT*8*64 + 255)/256), dim3(256), 0, stream>>>(We2, be2, Bg);
  k_edge_mlp<<<dim3(Epad/64), dim3(256), 0, stream>>>(ea, We1, be1, AgT, E, Epad);
  hipMemsetAsync(agg, 0, (size_t)N*64*4, stream);

  float* hc = h_a; float* hn = h_b;
  for (int it = 0; it < NITERS; ++it){
    k_msg_mfma<<<dim3(nblk128), dim3(512), 0, stream>>>(ei, hc, AgT, Bg, agg, E, Epad);
    k_combine<<<dim3((N + 63)/64), dim3(256), 0, stream>>>(
        hc, agg, root, convb, WihT, WhhT, bih, bhh, hn, N);
    float* tmp = hc; hc = hn; hn = tmp;
  }

  k_final<<<dim3((N + 63)/64), dim3(256), 0, stream>>>(
      hc, x, ext, Wo1, bo1, Wo2, bo2, Wc1, bc1, Wc2, bc2, fg_out, pred_out, N);
}